// Round 10
// baseline (43.102 us; speedup 1.0000x reference)
//
#include <hip/hip_runtime.h>

#define SEQ 256
#define NENV 64
#define NGROUPS 12
#define GDIM 128
#define ROWS (SEQ * NENV)           // 16384
#define TPB 512                     // 8 waves per block
#define WPB 8                       // waves (= rows) per block
#define NBLOCKS (ROWS / WPB)        // 2048

// Single fused kernel, single-barrier fold.
// Fold: thread tid owns Wg row r=tid>>2, 32-col chunk c=tid&3; in-lane dot,
// 2-shuffle reduce across chunk-threads, one LDS write, ONE barrier.
// Phase C: R7-verbatim row body (measured-fastest variant).
__global__ __launch_bounds__(TPB, 4)
void group_attn_fused(const float* __restrict__ ge,     // (ROWS, 12, 128)
                      const float* __restrict__ Wg,     // (128, 128)
                      const float* __restrict__ Wa,     // (256, 1)
                      float* __restrict__ out_weighted, // (ROWS, 128)
                      float* __restrict__ out_weights)  // (ROWS, 12)
{
    __shared__ float v_lds[GDIM];

    const int tid  = threadIdx.x;
    const int wave = tid >> 6;
    const int lane = tid & 63;
    const int row  = blockIdx.x * WPB + wave;
    const int half = lane >> 5;     // 0: even groups, 1: odd groups
    const int l32  = lane & 31;     // dims [l32*4, l32*4+3]

    // ---- Fold loads first (L2-hot): thread tid reads float4s [8*tid, 8*tid+8)
    // of Wg (consecutive across threads) and its 8 wa quads.
    const float4* wg4 = reinterpret_cast<const float4*>(Wg);     // 4096 quads
    const float4* wa4 = reinterpret_cast<const float4*>(Wa + 128);
    const int c = tid & 3;

    float4 wgq[8], waq[8];
#pragma unroll
    for (int k = 0; k < 8; ++k) wgq[k] = wg4[8 * tid + k];
#pragma unroll
    for (int k = 0; k < 8; ++k) waq[k] = wa4[c * 8 + k];

    // ---- ge loads issued while fold computes (needed only after barrier).
    const float* base = ge + (size_t)row * (NGROUPS * GDIM) + lane * 4;
    float4 g[6];
#pragma unroll
    for (int t = 0; t < 6; ++t)
        g[t] = *reinterpret_cast<const float4*>(base + t * 256);

    // ---- Fold compute: in-lane chunk dot + 2-shuffle reduce + 1 LDS write.
    {
        float p = 0.0f;
#pragma unroll
        for (int k = 0; k < 8; ++k) {
            p += wgq[k].x * waq[k].x + wgq[k].y * waq[k].y
               + wgq[k].z * waq[k].z + wgq[k].w * waq[k].w;
        }
        p += __shfl_xor(p, 1);
        p += __shfl_xor(p, 2);
        if (c == 0) v_lds[tid >> 2] = p;
    }
    __syncthreads();

    const float4 vf = *reinterpret_cast<const float4*>(&v_lds[l32 * 4]);

    // ---- Phase C: R7-verbatim row body (shuffle butterfly).
    float sc[12];
#pragma unroll
    for (int t = 0; t < 6; ++t) {
        float p = g[t].x * vf.x + g[t].y * vf.y + g[t].z * vf.z + g[t].w * vf.w;
        p += __shfl_xor(p, 1);
        p += __shfl_xor(p, 2);
        p += __shfl_xor(p, 4);
        p += __shfl_xor(p, 8);
        p += __shfl_xor(p, 16);
        float q = __shfl_xor(p, 32);
        sc[2 * t]     = half ? q : p;
        sc[2 * t + 1] = half ? p : q;
    }

    float m = sc[0];
#pragma unroll
    for (int i = 1; i < NGROUPS; ++i) m = fmaxf(m, sc[i]);
    float w[12];
    float sum = 0.0f;
#pragma unroll
    for (int i = 0; i < NGROUPS; ++i) {
        w[i] = __expf(sc[i] - m);
        sum += w[i];
    }
    const float inv = 1.0f / sum;
#pragma unroll
    for (int i = 0; i < NGROUPS; ++i) w[i] *= inv;

    float4 acc = make_float4(0.f, 0.f, 0.f, 0.f);
#pragma unroll
    for (int t = 0; t < 6; ++t) {
        const float wt = w[2 * t + half];
        acc.x += wt * g[t].x;
        acc.y += wt * g[t].y;
        acc.z += wt * g[t].z;
        acc.w += wt * g[t].w;
    }
    acc.x += __shfl_xor(acc.x, 32);
    acc.y += __shfl_xor(acc.y, 32);
    acc.z += __shfl_xor(acc.z, 32);
    acc.w += __shfl_xor(acc.w, 32);

    if (lane < 32) {
        *reinterpret_cast<float4*>(out_weighted + (size_t)row * GDIM + l32 * 4) = acc;
    } else if (lane < 32 + NGROUPS) {
        out_weights[(size_t)row * NGROUPS + (lane - 32)] = w[lane - 32];
    }
}

extern "C" void kernel_launch(void* const* d_in, const int* in_sizes, int n_in,
                              void* d_out, int out_size, void* d_ws, size_t ws_size,
                              hipStream_t stream) {
    // Inputs: 0 robot_states (unused) 1 group_embeddings 2 Wr (unused)
    // 3 br (unused) 4 Wg 5 bg (unused) 6 Wa 7 ba (unused)
    const float* ge = (const float*)d_in[1];
    const float* Wg = (const float*)d_in[4];
    const float* Wa = (const float*)d_in[6];

    float* out_weighted = (float*)d_out;                       // ROWS*128
    float* out_weights  = out_weighted + (size_t)ROWS * GDIM;  // ROWS*12

    group_attn_fused<<<NBLOCKS, TPB, 0, stream>>>(
        ge, Wg, Wa, out_weighted, out_weights);
}

// Round 11
// 24.017 us; speedup vs baseline: 1.7947x; 1.7947x over previous
//
#include <hip/hip_runtime.h>

#define SEQ 256
#define NENV 64
#define NGROUPS 12
#define GDIM 128
#define ROWS (SEQ * NENV)           // 16384
#define TPB 512                     // 8 waves per block
#define WPB 8                       // waves (= rows) per block
#define NBLOCKS (ROWS / WPB)        // 2048

// Single fused kernel (R9 == best measured, 23.62us).
// Phase A (per wave): issue the 6 ge row loads (independent of v).
// Phase B (per block): COALESCED fold v = Wg @ Wa[128:256] into LDS
//   (lane-consecutive float4s — coalescing here is the critical property;
//    R4/R10 showed lane-strided variants cost 20+us).
// Phase C (per wave): R7-verbatim row body (measured-fastest variant).
__global__ __launch_bounds__(TPB, 8)
void group_attn_fused(const float* __restrict__ ge,     // (ROWS, 12, 128)
                      const float* __restrict__ Wg,     // (128, 128)
                      const float* __restrict__ Wa,     // (256, 1)
                      float* __restrict__ out_weighted, // (ROWS, 128)
                      float* __restrict__ out_weights)  // (ROWS, 12)
{
    __shared__ float p1[4096];      // quad partials (16 KB)
    __shared__ float p2[4][128];    // stage-2 partials (2 KB)
    __shared__ float v_lds[GDIM];

    const int tid  = threadIdx.x;
    const int wave = tid >> 6;
    const int lane = tid & 63;
    const int row  = blockIdx.x * WPB + wave;
    const int half = lane >> 5;     // 0: even groups, 1: odd groups
    const int l32  = lane & 31;     // dims [l32*4, l32*4+3]

    // ---- Phase A: issue ge loads first; latency hides under the fold.
    const float* base = ge + (size_t)row * (NGROUPS * GDIM) + lane * 4;
    float4 g[6];
#pragma unroll
    for (int t = 0; t < 6; ++t)
        g[t] = *reinterpret_cast<const float4*>(base + t * 256);

    // ---- Phase B: fold prologue (coalesced), v = Wg @ Wa[128:256].
    // Thread tid handles quads {tid + 512k}, k=0..7; quad q covers columns
    // 4*(q%32) of row q/32, and q%32 == tid%32 (512 % 32 == 0).
    {
        const float4* wg4 = reinterpret_cast<const float4*>(Wg);     // 4096 quads
        const float4  waf = reinterpret_cast<const float4*>(Wa + 128)[tid & 31];
#pragma unroll
        for (int k = 0; k < 8; ++k) {
            const int q = tid + TPB * k;
            const float4 f = wg4[q];
            p1[q] = f.x * waf.x + f.y * waf.y + f.z * waf.z + f.w * waf.w;
        }
    }
    __syncthreads();
    {
        // 4 threads per output dim d: each sums 8 quad-partials (2 b128 reads).
        const int d = tid >> 2, sub = tid & 3;
        const float4 r0 = *reinterpret_cast<const float4*>(&p1[d * 32 + sub * 8]);
        const float4 r1 = *reinterpret_cast<const float4*>(&p1[d * 32 + sub * 8 + 4]);
        p2[sub][d] = (r0.x + r0.y + r0.z + r0.w) + (r1.x + r1.y + r1.z + r1.w);
    }
    __syncthreads();
    if (tid < GDIM) {
        v_lds[tid] = (p2[0][tid] + p2[1][tid]) + (p2[2][tid] + p2[3][tid]);
    }
    __syncthreads();

    const float4 vf = *reinterpret_cast<const float4*>(&v_lds[l32 * 4]);

    // ---- Phase C: R7-verbatim row body (shuffle butterfly).
    float sc[12];
#pragma unroll
    for (int t = 0; t < 6; ++t) {
        float p = g[t].x * vf.x + g[t].y * vf.y + g[t].z * vf.z + g[t].w * vf.w;
        p += __shfl_xor(p, 1);
        p += __shfl_xor(p, 2);
        p += __shfl_xor(p, 4);
        p += __shfl_xor(p, 8);
        p += __shfl_xor(p, 16);
        float q = __shfl_xor(p, 32);
        sc[2 * t]     = half ? q : p;
        sc[2 * t + 1] = half ? p : q;
    }

    float m = sc[0];
#pragma unroll
    for (int i = 1; i < NGROUPS; ++i) m = fmaxf(m, sc[i]);
    float w[12];
    float sum = 0.0f;
#pragma unroll
    for (int i = 0; i < NGROUPS; ++i) {
        w[i] = __expf(sc[i] - m);
        sum += w[i];
    }
    const float inv = 1.0f / sum;
#pragma unroll
    for (int i = 0; i < NGROUPS; ++i) w[i] *= inv;

    float4 acc = make_float4(0.f, 0.f, 0.f, 0.f);
#pragma unroll
    for (int t = 0; t < 6; ++t) {
        const float wt = w[2 * t + half];
        acc.x += wt * g[t].x;
        acc.y += wt * g[t].y;
        acc.z += wt * g[t].z;
        acc.w += wt * g[t].w;
    }
    acc.x += __shfl_xor(acc.x, 32);
    acc.y += __shfl_xor(acc.y, 32);
    acc.z += __shfl_xor(acc.z, 32);
    acc.w += __shfl_xor(acc.w, 32);

    if (lane < 32) {
        *reinterpret_cast<float4*>(out_weighted + (size_t)row * GDIM + l32 * 4) = acc;
    } else if (lane < 32 + NGROUPS) {
        out_weights[(size_t)row * NGROUPS + (lane - 32)] = w[lane - 32];
    }
}

extern "C" void kernel_launch(void* const* d_in, const int* in_sizes, int n_in,
                              void* d_out, int out_size, void* d_ws, size_t ws_size,
                              hipStream_t stream) {
    // Inputs: 0 robot_states (unused) 1 group_embeddings 2 Wr (unused)
    // 3 br (unused) 4 Wg 5 bg (unused) 6 Wa 7 ba (unused)
    const float* ge = (const float*)d_in[1];
    const float* Wg = (const float*)d_in[4];
    const float* Wa = (const float*)d_in[6];

    float* out_weighted = (float*)d_out;                       // ROWS*128
    float* out_weights  = out_weighted + (size_t)ROWS * GDIM;  // ROWS*12

    group_attn_fused<<<NBLOCKS, TPB, 0, stream>>>(
        ge, Wg, Wa, out_weighted, out_weights);
}